// Round 2
// baseline (11966.711 us; speedup 1.0000x reference)
//
#include <hip/hip_runtime.h>
#include <stdint.h>

#define B_SZ 128
#define SEQL 1024
#define EMB  64
#define HID  512
#define VOC  96

typedef __attribute__((ext_vector_type(8))) short bf16x8;
typedef __attribute__((ext_vector_type(4))) float f32x4;

__device__ __forceinline__ float bf2f(ushort u) {
  union { uint32_t i; float f; } c; c.i = ((uint32_t)u) << 16; return c.f;
}
__device__ __forceinline__ ushort f2bf(float f) {
  union { float f; uint32_t i; } c; c.f = f;
  uint32_t u = c.i;
  return (ushort)((u + 0x7fffu + ((u >> 16) & 1u)) >> 16);
}
__device__ __forceinline__ float fast_tanh(float v) {
  float e = __expf(2.0f * v);
  return (e - 1.0f) * __builtin_amdgcn_rcpf(e + 1.0f);
}

// ---- dtype detection: flags[0] = 0 (bf16 arrays) / 1 (f32 arrays);
//      flags[1] = x int32 stride (1) or int64 stride (2) ----
__global__ void detect_kernel(const ushort* __restrict__ emb_u16,
                              const int* __restrict__ x32, int* __restrict__ flags) {
  if (threadIdx.x != 0 || blockIdx.x != 0) return;
  int wild = 0;
  for (int i = 0; i < 256; ++i) {          // bf16 N(0,1): exponent 117..130, never wild
    ushort u = emb_u16[i];                 // f32-as-ushort: mantissa halves -> wild exponents
    int ex = (u >> 7) & 0xFF;
    if (u != 0 && (ex < 96 || ex > 159)) wild++;
  }
  flags[0] = (wild > 8) ? 1 : 0;
  int allz = 1, anynz = 0;
  for (int i = 0; i < 64; ++i) {           // int64 little-endian: odd words are 0
    if (x32[2 * i + 1] != 0) allz = 0;
    if (x32[2 * i] != 0) anynz = 1;
  }
  flags[1] = (allz && anynz) ? 2 : 1;
}

// ---- embWb[v][h] = sum_e emb[v][e]*W_xh[e][h] + b_h[h] (f32, full precision) ----
template <int MODE>
__global__ void prep_embw(const void* __restrict__ embp, const void* __restrict__ wxhp,
                          const void* __restrict__ bhp, const int* __restrict__ flags,
                          float* __restrict__ embwb) {
  if (flags[0] != MODE) return;
  int gt = blockIdx.x * 256 + threadIdx.x;   // 96*512 threads
  int v = gt >> 9, h = gt & 511;
  float s;
  if (MODE == 0) {
    const ushort* emb = (const ushort*)embp;
    const ushort* wxh = (const ushort*)wxhp;
    s = bf2f(((const ushort*)bhp)[h]);
#pragma unroll 8
    for (int e = 0; e < EMB; ++e) s += bf2f(emb[v * EMB + e]) * bf2f(wxh[e * HID + h]);
  } else {
    const float* emb = (const float*)embp;
    const float* wxh = (const float*)wxhp;
    s = ((const float*)bhp)[h];
#pragma unroll 8
    for (int e = 0; e < EMB; ++e) s += emb[v * EMB + e] * wxh[e * HID + h];
  }
  embwb[gt] = s;
}

// ---- swizzle [512 x ncols] k-major weight into MFMA B-fragment-major bf16 ----
template <int MODE>
__global__ void prep_frag(const void* __restrict__ Wp, const int* __restrict__ flags,
                          ushort* __restrict__ out, int ncols) {
  if (flags[0] != MODE) return;
  int t = blockIdx.x * 256 + threadIdx.x;    // NT*16*64 threads
  int lane = t & 63, kt = (t >> 6) & 15, nt = t >> 10;
  int n = nt * 16 + (lane & 15);
  int k0 = kt * 32 + (lane >> 4) * 8;
  ushort* o = out + (size_t)t * 8;
  if (MODE == 0) {
    const ushort* W = (const ushort*)Wp;
#pragma unroll
    for (int j = 0; j < 8; ++j) o[j] = W[(size_t)(k0 + j) * ncols + n];
  } else {
    const float* W = (const float*)Wp;
#pragma unroll
    for (int j = 0; j < 8; ++j) o[j] = f2bf(W[(size_t)(k0 + j) * ncols + n]);
  }
}

// ---- fused recurrence + logits: 8 blocks x 256 threads; block b owns rows 16b..16b+15.
// At step t, A-fragments hold h_{t-1}: used for BOTH h_t GEMM and logits_{t-1}. ----
template <int MODE>
__global__ __launch_bounds__(256, 1) void rnn_fused(
    const int* __restrict__ x, const void* __restrict__ hiddenp,
    const float* __restrict__ embwb, const ushort* __restrict__ wf,
    const ushort* __restrict__ fwf, const void* __restrict__ fcbp,
    const int* __restrict__ flags, void* __restrict__ outp) {
  if (flags[0] != MODE) return;
  const int xstr = flags[1];
  __shared__ __align__(16) ushort hlds[64 * 128];   // [g=k/8][m][8], 16 KB
  __shared__ float biasl[VOC];
  const int tid = threadIdx.x;
  const int wid = tid >> 6, lane = tid & 63;
  const int q = lane >> 4, l15 = lane & 15;
  const int rbase = blockIdx.x * 16;

  if (tid < VOC)
    biasl[tid] = (MODE == 0) ? bf2f(((const ushort*)fcbp)[tid]) : ((const float*)fcbp)[tid];

  // init h_0
#pragma unroll
  for (int it = 0; it < 4; ++it) {
    int idx = it * 256 + tid;
    int m = idx & 15, g = idx >> 4;
    if (MODE == 0) {
      uint4 v = *(const uint4*)&((const ushort*)hiddenp)[(size_t)(rbase + m) * HID + g * 8];
      *(uint4*)&hlds[g * 128 + m * 8] = v;
    } else {
      const float* hf = (const float*)hiddenp;
#pragma unroll
      for (int j = 0; j < 8; ++j)
        hlds[g * 128 + m * 8 + j] = f2bf(hf[(size_t)(rbase + m) * HID + g * 8 + j]);
    }
  }

  const uint4* Wf4 = (const uint4*)wf;
  const uint4* Ff4 = (const uint4*)fwf;
  float* outf = (float*)outp;
  ushort* outb = (ushort*)outp;
  const int lt0 = (wid < 2) ? wid * 2 : (2 + wid);   // waves: {0,1},{2,3},{4},{5}
  const int nlt = (wid < 2) ? 2 : 1;

#pragma unroll 1
  for (int t = 0; t < SEQL; ++t) {
    __syncthreads();                        // h_{t-1} stable in LDS
    bf16x8 a[16];
#pragma unroll
    for (int kt = 0; kt < 16; ++kt)
      a[kt] = *(const bf16x8*)&hlds[(kt * 4 + q) * 128 + l15 * 8];
    int xi[4];
#pragma unroll
    for (int rg = 0; rg < 4; ++rg)
      xi[rg] = x[(size_t)((rbase + q * 4 + rg) * SEQL + t) * xstr];
    __syncthreads();                        // reads of h_{t-1} complete

    // logits for step t-1 (A-frags already hold h_{t-1})
    if (t > 0) {
      for (int i = 0; i < nlt; ++i) {
        int lt = lt0 + i;
        f32x4 c = {0.f, 0.f, 0.f, 0.f};
        const uint4* Bp = Ff4 + (size_t)lt * 1024 + lane;
#pragma unroll
        for (int kt = 0; kt < 16; ++kt)
          c = __builtin_amdgcn_mfma_f32_16x16x32_bf16(a[kt], *(const bf16x8*)(Bp + kt * 64), c, 0, 0, 0);
        int n = lt * 16 + l15;
        float bv = biasl[n];
#pragma unroll
        for (int rg = 0; rg < 4; ++rg) {
          size_t idx = ((size_t)(rbase + q * 4 + rg) * SEQL + (t - 1)) * VOC + n;
          float val = c[rg] + bv;
          if (MODE == 0) outb[idx] = f2bf(val); else outf[idx] = val;
        }
      }
    }

    // h_t = tanh(embWb[x_t] + h_{t-1} @ W_hh)
#pragma unroll
    for (int p = 0; p < 4; ++p) {
      const int nt0 = wid * 8 + 2 * p;
      f32x4 c0 = {0.f, 0.f, 0.f, 0.f}, c1 = {0.f, 0.f, 0.f, 0.f};
      const uint4* B0 = Wf4 + (size_t)(nt0 * 16) * 64 + lane;
      const uint4* B1 = B0 + 16 * 64;
#pragma unroll
      for (int kt = 0; kt < 16; ++kt) {
        bf16x8 b0 = *(const bf16x8*)(B0 + kt * 64);
        bf16x8 b1 = *(const bf16x8*)(B1 + kt * 64);
        c0 = __builtin_amdgcn_mfma_f32_16x16x32_bf16(a[kt], b0, c0, 0, 0, 0);
        c1 = __builtin_amdgcn_mfma_f32_16x16x32_bf16(a[kt], b1, c1, 0, 0, 0);
      }
#pragma unroll
      for (int half = 0; half < 2; ++half) {
        const int nt = nt0 + half;
        f32x4 c = half ? c1 : c0;
        const int n = nt * 16 + l15;
        const int goff = (n >> 3) * 128 + (n & 7);
#pragma unroll
        for (int rg = 0; rg < 4; ++rg) {
          float pre = c[rg] + embwb[(size_t)xi[rg] * HID + n];
          hlds[goff + (q * 4 + rg) * 8] = f2bf(fast_tanh(pre));
        }
      }
    }
  }

  __syncthreads();                          // h_1023 stable
  {
    bf16x8 a[16];
#pragma unroll
    for (int kt = 0; kt < 16; ++kt)
      a[kt] = *(const bf16x8*)&hlds[(kt * 4 + q) * 128 + l15 * 8];
    for (int i = 0; i < nlt; ++i) {
      int lt = lt0 + i;
      f32x4 c = {0.f, 0.f, 0.f, 0.f};
      const uint4* Bp = Ff4 + (size_t)lt * 1024 + lane;
#pragma unroll
      for (int kt = 0; kt < 16; ++kt)
        c = __builtin_amdgcn_mfma_f32_16x16x32_bf16(a[kt], *(const bf16x8*)(Bp + kt * 64), c, 0, 0, 0);
      int n = lt * 16 + l15;
      float bv = biasl[n];
#pragma unroll
      for (int rg = 0; rg < 4; ++rg) {
        size_t idx = ((size_t)(rbase + q * 4 + rg) * SEQL + (SEQL - 1)) * VOC + n;
        float val = c[rg] + bv;
        if (MODE == 0) outb[idx] = f2bf(val); else outf[idx] = val;
      }
    }
  }
  // final hidden state -> out tail
#pragma unroll
  for (int it = 0; it < 4; ++it) {
    int idx = it * 256 + tid;
    int m = idx & 15, g = idx >> 4;
    if (MODE == 0) {
      uint4 v = *(const uint4*)&hlds[g * 128 + m * 8];
      *(uint4*)&(outb + (size_t)B_SZ * SEQL * VOC)[(size_t)(rbase + m) * HID + g * 8] = v;
    } else {
      float* fh = outf + (size_t)B_SZ * SEQL * VOC;
#pragma unroll
      for (int j = 0; j < 8; ++j)
        fh[(size_t)(rbase + m) * HID + g * 8 + j] = bf2f(hlds[g * 128 + m * 8 + j]);
    }
  }
}

extern "C" void kernel_launch(void* const* d_in, const int* in_sizes, int n_in,
                              void* d_out, int out_size, void* d_ws, size_t ws_size,
                              hipStream_t stream) {
  const void* x      = d_in[0];
  const void* hidden = d_in[1];
  const void* emb    = d_in[2];
  const void* wxh    = d_in[3];
  const void* whh    = d_in[4];
  const void* bh     = d_in[5];
  const void* fcw    = d_in[6];
  const void* fcb    = d_in[7];

  char* ws = (char*)d_ws;
  int*    flags  = (int*)ws;                       // 256 B reserved
  float*  embwb  = (float*)(ws + 256);             // 196608 B
  ushort* wfrag  = (ushort*)(ws + 256 + 196608);   // 524288 B
  ushort* fwfrag = (ushort*)(ws + 256 + 196608 + 524288); // 98304 B

  detect_kernel<<<1, 64, 0, stream>>>((const ushort*)emb, (const int*)x, flags);

  prep_embw<0><<<192, 256, 0, stream>>>(emb, wxh, bh, flags, embwb);
  prep_embw<1><<<192, 256, 0, stream>>>(emb, wxh, bh, flags, embwb);
  prep_frag<0><<<128, 256, 0, stream>>>(whh, flags, wfrag, HID);
  prep_frag<1><<<128, 256, 0, stream>>>(whh, flags, wfrag, HID);
  prep_frag<0><<<24, 256, 0, stream>>>(fcw, flags, fwfrag, VOC);
  prep_frag<1><<<24, 256, 0, stream>>>(fcw, flags, fwfrag, VOC);

  rnn_fused<0><<<8, 256, 0, stream>>>((const int*)x, hidden, embwb, wfrag, fwfrag, fcb, flags, d_out);
  rnn_fused<1><<<8, 256, 0, stream>>>((const int*)x, hidden, embwb, wfrag, fwfrag, fcb, flags, d_out);
}

// Round 3
// 4822.698 us; speedup vs baseline: 2.4813x; 2.4813x over previous
//
#include <hip/hip_runtime.h>
#include <stdint.h>

#define B_SZ 128
#define SEQL 1024
#define EMB  64
#define HID  512
#define VOC  96

typedef __attribute__((ext_vector_type(8))) short bf16x8;
typedef __attribute__((ext_vector_type(4))) float f32x4;

__device__ __forceinline__ float bf2f(ushort u) {
  union { uint32_t i; float f; } c; c.i = ((uint32_t)u) << 16; return c.f;
}
__device__ __forceinline__ ushort f2bf(float f) {
  union { float f; uint32_t i; } c; c.f = f;
  uint32_t u = c.i;
  return (ushort)((u + 0x7fffu + ((u >> 16) & 1u)) >> 16);
}
__device__ __forceinline__ float fast_tanh(float v) {
  float e = __expf(2.0f * v);
  return (e - 1.0f) * __builtin_amdgcn_rcpf(e + 1.0f);
}

// flags[0]=dtype mode (0 bf16 / 1 f32); flags[1]=x stride (1 int32 / 2 int64);
// flags[16..31] = per-block sync flags (zeroed here every launch).
__global__ void detect_kernel(const ushort* __restrict__ emb_u16,
                              const int* __restrict__ x32, int* __restrict__ flags) {
  if (blockIdx.x != 0) return;
  if (threadIdx.x < 32) flags[16 + threadIdx.x] = 0;
  if (threadIdx.x != 0) return;
  int wild = 0;
  for (int i = 0; i < 256; ++i) {
    ushort u = emb_u16[i];
    int ex = (u >> 7) & 0xFF;
    if (u != 0 && (ex < 96 || ex > 159)) wild++;
  }
  flags[0] = (wild > 8) ? 1 : 0;
  int allz = 1, anynz = 0;
  for (int i = 0; i < 64; ++i) {
    if (x32[2 * i + 1] != 0) allz = 0;
    if (x32[2 * i] != 0) anynz = 1;
  }
  flags[1] = (allz && anynz) ? 2 : 1;
}

// embWb[v][h] = sum_e emb[v][e]*W_xh[e][h] + b_h[h]  (f32)
template <int MODE>
__global__ void prep_embw(const void* __restrict__ embp, const void* __restrict__ wxhp,
                          const void* __restrict__ bhp, const int* __restrict__ flags,
                          float* __restrict__ embwb) {
  if (flags[0] != MODE) return;
  int gt = blockIdx.x * 256 + threadIdx.x;
  int v = gt >> 9, h = gt & 511;
  float s;
  if (MODE == 0) {
    const ushort* emb = (const ushort*)embp;
    const ushort* wxh = (const ushort*)wxhp;
    s = bf2f(((const ushort*)bhp)[h]);
#pragma unroll 8
    for (int e = 0; e < EMB; ++e) s += bf2f(emb[v * EMB + e]) * bf2f(wxh[e * HID + h]);
  } else {
    const float* emb = (const float*)embp;
    const float* wxh = (const float*)wxhp;
    s = ((const float*)bhp)[h];
#pragma unroll 8
    for (int e = 0; e < EMB; ++e) s += emb[v * EMB + e] * wxh[e * HID + h];
  }
  embwb[gt] = s;
}

// swizzle [512 x ncols] k-major weight into MFMA B-fragment-major bf16
template <int MODE>
__global__ void prep_frag(const void* __restrict__ Wp, const int* __restrict__ flags,
                          ushort* __restrict__ out, int ncols) {
  if (flags[0] != MODE) return;
  int t = blockIdx.x * 256 + threadIdx.x;
  int lane = t & 63, kt = (t >> 6) & 15, nt = t >> 10;
  int n = nt * 16 + (lane & 15);
  int k0 = kt * 32 + (lane >> 4) * 8;
  ushort* o = out + (size_t)t * 8;
  if (MODE == 0) {
    const ushort* W = (const ushort*)Wp;
#pragma unroll
    for (int j = 0; j < 8; ++j) o[j] = W[(size_t)(k0 + j) * ncols + n];
  } else {
    const float* W = (const float*)Wp;
#pragma unroll
    for (int j = 0; j < 8; ++j) o[j] = f2bf(W[(size_t)(k0 + j) * ncols + n]);
  }
}

// ---- recurrence, 2-way N-split with register-persistent W_hh halves ----
// 16 blocks x 512 thr. rg = bx&7 (batch rows rg*16..+16), s = bx>>3 (N-half).
// Pair (bx, bx^8) exchanges h halves each step via gbuf + step-indexed flags.
#define LDS_G 136   // padded [g][m][8] stride (elements) per g
template <int MODE>
__global__ __launch_bounds__(512, 2) void rnn_split(
    const int* __restrict__ x, const void* __restrict__ hiddenp,
    const float* __restrict__ embwb, const ushort* __restrict__ wf,
    const ushort* __restrict__ fwf, const void* __restrict__ fcbp,
    int* __restrict__ flags, ushort* __restrict__ gbuf, void* __restrict__ outp) {
  if (flags[0] != MODE) return;
  const int xstr = flags[1];
  __shared__ __align__(16) ushort hlds[32 * LDS_G + 8];
  __shared__ float biasl[VOC];
  const int tid = threadIdx.x;
  const int wid = tid >> 6, lane = tid & 63;
  const int q = lane >> 4, l15 = lane & 15;
  const int rg = blockIdx.x & 7, s = blockIdx.x >> 3;
  const int rbase = rg * 16;
  int* flag_me = flags + 16 + blockIdx.x;
  int* flag_pt = flags + 16 + (blockIdx.x ^ 8);
  ushort* buf_me = gbuf + (size_t)blockIdx.x * 2 * 4096;
  const ushort* buf_pt = gbuf + (size_t)(blockIdx.x ^ 8) * 2 * 4096;

  if (tid < VOC)
    biasl[tid] = (MODE == 0) ? bf2f(((const ushort*)fcbp)[tid]) : ((const float*)fcbp)[tid];

  // persistent W_hh fragments: wave owns global N-tiles nt0, nt0+1, full K.
  const int nt0 = s * 16 + 2 * wid;
  const uint4* Wf4 = (const uint4*)wf;
  bf16x8 Bo[2][8], Bp[2][8];
#pragma unroll
  for (int j = 0; j < 2; ++j)
#pragma unroll
    for (int ktl = 0; ktl < 8; ++ktl) {
      Bo[j][ktl] = *(const bf16x8*)(Wf4 + ((size_t)(nt0 + j) * 16 + (s * 8 + ktl)) * 64 + lane);
      Bp[j][ktl] = *(const bf16x8*)(Wf4 + ((size_t)(nt0 + j) * 16 + ((1 - s) * 8 + ktl)) * 64 + lane);
    }

  // stage own half of h_{-1}=hidden into LDS + publish to gbuf parity 1
  {
    int g = tid >> 4, m = tid & 15;
    uint4 v;
    if (MODE == 0) {
      v = *(const uint4*)&((const ushort*)hiddenp)[(size_t)(rbase + m) * HID + s * 256 + g * 8];
    } else {
      const float* hf = (const float*)hiddenp;
      ushort tmp[8];
#pragma unroll
      for (int j = 0; j < 8; ++j) tmp[j] = f2bf(hf[(size_t)(rbase + m) * HID + s * 256 + g * 8 + j]);
      v = *(const uint4*)tmp;
    }
    *(uint4*)&hlds[g * LDS_G + m * 8] = v;
    *(uint4*)&buf_me[4096 + g * 128 + m * 8] = v;
  }
  __syncthreads();   // all waves drained (vmcnt) before publish
  if (tid == 0) {
    __threadfence();
    __hip_atomic_store(flag_me, 1, __ATOMIC_RELEASE, __HIP_MEMORY_SCOPE_AGENT);
  }

  const uint4* Ff4 = (const uint4*)fwf;
  float* outf = (float*)outp;
  ushort* outb = (ushort*)outp;
  const bool lw = (wid >= 5);
  const int lt = s * 3 + (wid - 5);   // logit tile, valid when lw

#pragma unroll 1
  for (int t = 0; t < SEQL; ++t) {
    const int need = t + 1;
    int fv = __hip_atomic_load(flag_pt, __ATOMIC_RELAXED, __HIP_MEMORY_SCOPE_AGENT);
    // own-half A fragments (h_{t-1} cols [s*256, s*256+256))
    bf16x8 a[8];
#pragma unroll
    for (int ktl = 0; ktl < 8; ++ktl)
      a[ktl] = *(const bf16x8*)&hlds[(ktl * 4 + q) * LDS_G + l15 * 8];
    int xi[4];
#pragma unroll
    for (int rgi = 0; rgi < 4; ++rgi)
      xi[rgi] = x[(size_t)((rbase + q * 4 + rgi) * SEQL + t) * xstr];
    float ew[2][4];
#pragma unroll
    for (int j = 0; j < 2; ++j) {
      int n = (nt0 + j) * 16 + l15;
#pragma unroll
      for (int rgi = 0; rgi < 4; ++rgi) ew[j][rgi] = embwb[(size_t)xi[rgi] * HID + n];
    }
    f32x4 c0 = {0.f, 0.f, 0.f, 0.f}, c1 = {0.f, 0.f, 0.f, 0.f}, lc = {0.f, 0.f, 0.f, 0.f};
#pragma unroll
    for (int ktl = 0; ktl < 8; ++ktl) {
      c0 = __builtin_amdgcn_mfma_f32_16x16x32_bf16(a[ktl], Bo[0][ktl], c0, 0, 0, 0);
      c1 = __builtin_amdgcn_mfma_f32_16x16x32_bf16(a[ktl], Bo[1][ktl], c1, 0, 0, 0);
    }
    if (lw) {
#pragma unroll
      for (int ktl = 0; ktl < 8; ++ktl) {
        bf16x8 f = *(const bf16x8*)(Ff4 + ((size_t)lt * 16 + s * 8 + ktl) * 64 + lane);
        lc = __builtin_amdgcn_mfma_f32_16x16x32_bf16(a[ktl], f, lc, 0, 0, 0);
      }
    }
    // wait for partner's h_{t-1} half
    while (fv < need) {
      __builtin_amdgcn_s_sleep(2);
      fv = __hip_atomic_load(flag_pt, __ATOMIC_RELAXED, __HIP_MEMORY_SCOPE_AGENT);
    }
    (void)__hip_atomic_load(flag_pt, __ATOMIC_ACQUIRE, __HIP_MEMORY_SCOPE_AGENT);
    const ushort* pb = buf_pt + ((size_t)((t + 1) & 1)) * 4096;  // parity of t-1
    bf16x8 ap[8];
#pragma unroll
    for (int ktl = 0; ktl < 8; ++ktl)
      ap[ktl] = *(const bf16x8*)&pb[(ktl * 4 + q) * 128 + l15 * 8];
#pragma unroll
    for (int ktl = 0; ktl < 8; ++ktl) {
      c0 = __builtin_amdgcn_mfma_f32_16x16x32_bf16(ap[ktl], Bp[0][ktl], c0, 0, 0, 0);
      c1 = __builtin_amdgcn_mfma_f32_16x16x32_bf16(ap[ktl], Bp[1][ktl], c1, 0, 0, 0);
    }
    if (lw) {
#pragma unroll
      for (int ktl = 0; ktl < 8; ++ktl) {
        bf16x8 f = *(const bf16x8*)(Ff4 + ((size_t)lt * 16 + (1 - s) * 8 + ktl) * 64 + lane);
        lc = __builtin_amdgcn_mfma_f32_16x16x32_bf16(ap[ktl], f, lc, 0, 0, 0);
      }
      if (t > 0) {
        int n = lt * 16 + l15;
        float bv = biasl[n];
#pragma unroll
        for (int rgi = 0; rgi < 4; ++rgi) {
          size_t idx = ((size_t)(rbase + q * 4 + rgi) * SEQL + (t - 1)) * VOC + n;
          float val = lc[rgi] + bv;
          if (MODE == 0) outb[idx] = f2bf(val); else outf[idx] = val;
        }
      }
    }
    // h_t = tanh(pre)
    ushort hv[2][4];
#pragma unroll
    for (int rgi = 0; rgi < 4; ++rgi) hv[0][rgi] = f2bf(fast_tanh(c0[rgi] + ew[0][rgi]));
#pragma unroll
    for (int rgi = 0; rgi < 4; ++rgi) hv[1][rgi] = f2bf(fast_tanh(c1[rgi] + ew[1][rgi]));
    __syncthreads();   // everyone done reading h_{t-1} from LDS
#pragma unroll
    for (int j = 0; j < 2; ++j) {
      int nl = (2 * wid + j) * 16 + l15;          // block-local col
      int base = (nl >> 3) * LDS_G + (nl & 7);
#pragma unroll
      for (int rgi = 0; rgi < 4; ++rgi) hlds[base + (q * 4 + rgi) * 8] = hv[j][rgi];
    }
    __syncthreads();   // h_t complete in LDS
    {
      int g = tid >> 4, m = tid & 15;
      *(uint4*)&buf_me[(size_t)(t & 1) * 4096 + g * 128 + m * 8] =
          *(const uint4*)&hlds[g * LDS_G + m * 8];
    }
    __syncthreads();   // every wave's stores drained (vmcnt) before flag
    if (tid == 0) {
      __threadfence();
      __hip_atomic_store(flag_me, t + 2, __ATOMIC_RELEASE, __HIP_MEMORY_SCOPE_AGENT);
    }
  }

  // epilogue: logits for t=1023 + final hidden state
  if (lw) {
    const int need = SEQL + 1;
    int fv = __hip_atomic_load(flag_pt, __ATOMIC_RELAXED, __HIP_MEMORY_SCOPE_AGENT);
    while (fv < need) {
      __builtin_amdgcn_s_sleep(2);
      fv = __hip_atomic_load(flag_pt, __ATOMIC_RELAXED, __HIP_MEMORY_SCOPE_AGENT);
    }
    (void)__hip_atomic_load(flag_pt, __ATOMIC_ACQUIRE, __HIP_MEMORY_SCOPE_AGENT);
    const ushort* pb = buf_pt + 4096;   // h_1023 parity = 1
    f32x4 lc = {0.f, 0.f, 0.f, 0.f};
#pragma unroll
    for (int ktl = 0; ktl < 8; ++ktl) {
      bf16x8 av = *(const bf16x8*)&hlds[(ktl * 4 + q) * LDS_G + l15 * 8];
      bf16x8 f = *(const bf16x8*)(Ff4 + ((size_t)lt * 16 + s * 8 + ktl) * 64 + lane);
      lc = __builtin_amdgcn_mfma_f32_16x16x32_bf16(av, f, lc, 0, 0, 0);
    }
#pragma unroll
    for (int ktl = 0; ktl < 8; ++ktl) {
      bf16x8 av = *(const bf16x8*)&pb[(ktl * 4 + q) * 128 + l15 * 8];
      bf16x8 f = *(const bf16x8*)(Ff4 + ((size_t)lt * 16 + (1 - s) * 8 + ktl) * 64 + lane);
      lc = __builtin_amdgcn_mfma_f32_16x16x32_bf16(av, f, lc, 0, 0, 0);
    }
    int n = lt * 16 + l15;
    float bv = biasl[n];
#pragma unroll
    for (int rgi = 0; rgi < 4; ++rgi) {
      size_t idx = ((size_t)(rbase + q * 4 + rgi) * SEQL + (SEQL - 1)) * VOC + n;
      float val = lc[rgi] + bv;
      if (MODE == 0) outb[idx] = f2bf(val); else outf[idx] = val;
    }
  }
  {
    int g = tid >> 4, m = tid & 15;
    if (MODE == 0) {
      *(uint4*)&outb[(size_t)B_SZ * SEQL * VOC + (size_t)(rbase + m) * HID + s * 256 + g * 8] =
          *(const uint4*)&hlds[g * LDS_G + m * 8];
    } else {
      float* fh = outf + (size_t)B_SZ * SEQL * VOC;
#pragma unroll
      for (int j = 0; j < 8; ++j)
        fh[(size_t)(rbase + m) * HID + s * 256 + g * 8 + j] = bf2f(hlds[g * LDS_G + m * 8 + j]);
    }
  }
}

extern "C" void kernel_launch(void* const* d_in, const int* in_sizes, int n_in,
                              void* d_out, int out_size, void* d_ws, size_t ws_size,
                              hipStream_t stream) {
  const void* x      = d_in[0];
  const void* hidden = d_in[1];
  const void* emb    = d_in[2];
  const void* wxh    = d_in[3];
  const void* whh    = d_in[4];
  const void* bh     = d_in[5];
  const void* fcw    = d_in[6];
  const void* fcb    = d_in[7];

  char* ws = (char*)d_ws;
  int*    flags  = (int*)ws;                                   // 256 B (incl. sync flags)
  float*  embwb  = (float*)(ws + 256);                         // 196608 B
  ushort* wfrag  = (ushort*)(ws + 256 + 196608);               // 524288 B
  ushort* fwfrag = (ushort*)(ws + 256 + 196608 + 524288);      // 98304 B
  ushort* gbuf   = (ushort*)(ws + 256 + 196608 + 524288 + 98304); // 262144 B

  detect_kernel<<<1, 64, 0, stream>>>((const ushort*)emb, (const int*)x, flags);

  prep_embw<0><<<192, 256, 0, stream>>>(emb, wxh, bh, flags, embwb);
  prep_embw<1><<<192, 256, 0, stream>>>(emb, wxh, bh, flags, embwb);
  prep_frag<0><<<128, 256, 0, stream>>>(whh, flags, wfrag, HID);
  prep_frag<1><<<128, 256, 0, stream>>>(whh, flags, wfrag, HID);
  prep_frag<0><<<24, 256, 0, stream>>>(fcw, flags, fwfrag, VOC);
  prep_frag<1><<<24, 256, 0, stream>>>(fcw, flags, fwfrag, VOC);

  rnn_split<0><<<16, 512, 0, stream>>>((const int*)x, hidden, embwb, wfrag, fwfrag, fcb, flags, gbuf, d_out);
  rnn_split<1><<<16, 512, 0, stream>>>((const int*)x, hidden, embwb, wfrag, fwfrag, fcb, flags, gbuf, d_out);
}

// Round 4
// 3719.766 us; speedup vs baseline: 3.2171x; 1.2965x over previous
//
#include <hip/hip_runtime.h>
#include <stdint.h>

#define B_SZ 128
#define SEQL 1024
#define EMB  64
#define HID  512
#define VOC  96

typedef __attribute__((ext_vector_type(8))) short bf16x8;
typedef __attribute__((ext_vector_type(4))) float f32x4;

__device__ __forceinline__ float bf2f(ushort u) {
  union { uint32_t i; float f; } c; c.i = ((uint32_t)u) << 16; return c.f;
}
__device__ __forceinline__ ushort f2bf(float f) {
  union { float f; uint32_t i; } c; c.f = f;
  uint32_t u = c.i;
  return (ushort)((u + 0x7fffu + ((u >> 16) & 1u)) >> 16);
}
__device__ __forceinline__ float fast_tanh(float v) {
  float e = __expf(2.0f * v);
  return (e - 1.0f) * __builtin_amdgcn_rcpf(e + 1.0f);
}

// flags[0]=dtype mode (0 bf16 / 1 f32); flags[1]=x stride (1 int32 / 2 int64);
// flags[16..31] = per-block sync flags (zeroed every launch).
__global__ void detect_kernel(const ushort* __restrict__ emb_u16,
                              const int* __restrict__ x32, int* __restrict__ flags) {
  if (blockIdx.x != 0) return;
  if (threadIdx.x < 32) flags[16 + threadIdx.x] = 0;
  if (threadIdx.x != 0) return;
  int wild = 0;
  for (int i = 0; i < 256; ++i) {
    ushort u = emb_u16[i];
    int ex = (u >> 7) & 0xFF;
    if (u != 0 && (ex < 96 || ex > 159)) wild++;
  }
  flags[0] = (wild > 8) ? 1 : 0;
  int allz = 1, anynz = 0;
  for (int i = 0; i < 64; ++i) {
    if (x32[2 * i + 1] != 0) allz = 0;
    if (x32[2 * i] != 0) anynz = 1;
  }
  flags[1] = (allz && anynz) ? 2 : 1;
}

template <int MODE>
__global__ void prep_embw(const void* __restrict__ embp, const void* __restrict__ wxhp,
                          const void* __restrict__ bhp, const int* __restrict__ flags,
                          float* __restrict__ embwb) {
  if (flags[0] != MODE) return;
  int gt = blockIdx.x * 256 + threadIdx.x;
  int v = gt >> 9, h = gt & 511;
  float s;
  if (MODE == 0) {
    const ushort* emb = (const ushort*)embp;
    const ushort* wxh = (const ushort*)wxhp;
    s = bf2f(((const ushort*)bhp)[h]);
#pragma unroll 8
    for (int e = 0; e < EMB; ++e) s += bf2f(emb[v * EMB + e]) * bf2f(wxh[e * HID + h]);
  } else {
    const float* emb = (const float*)embp;
    const float* wxh = (const float*)wxhp;
    s = ((const float*)bhp)[h];
#pragma unroll 8
    for (int e = 0; e < EMB; ++e) s += emb[v * EMB + e] * wxh[e * HID + h];
  }
  embwb[gt] = s;
}

template <int MODE>
__global__ void prep_frag(const void* __restrict__ Wp, const int* __restrict__ flags,
                          ushort* __restrict__ out, int ncols) {
  if (flags[0] != MODE) return;
  int t = blockIdx.x * 256 + threadIdx.x;
  int lane = t & 63, kt = (t >> 6) & 15, nt = t >> 10;
  int n = nt * 16 + (lane & 15);
  int k0 = kt * 32 + (lane >> 4) * 8;
  ushort* o = out + (size_t)t * 8;
  if (MODE == 0) {
    const ushort* W = (const ushort*)Wp;
#pragma unroll
    for (int j = 0; j < 8; ++j) o[j] = W[(size_t)(k0 + j) * ncols + n];
  } else {
    const float* W = (const float*)Wp;
#pragma unroll
    for (int j = 0; j < 8; ++j) o[j] = f2bf(W[(size_t)(k0 + j) * ncols + n]);
  }
}

// ---- recurrence, 2-way N-split, register-persistent W_hh halves,
//      fence-free SYSTEM-relaxed (sc0sc1) h-exchange ----
#define LDS_G 136
template <int MODE>
__global__ __launch_bounds__(512, 2) void rnn_split(
    const int* __restrict__ x, const void* __restrict__ hiddenp,
    const float* __restrict__ embwb, const ushort* __restrict__ wf,
    const ushort* __restrict__ fwf, const void* __restrict__ fcbp,
    int* __restrict__ flags, ushort* __restrict__ gbuf, void* __restrict__ outp) {
  if (flags[0] != MODE) return;
  const int xstr = flags[1];
  __shared__ __align__(16) ushort hlds[2][32 * LDS_G + 8];
  __shared__ float biasl[VOC];
  const int tid = threadIdx.x;
  const int wid = tid >> 6, lane = tid & 63;
  const int q = lane >> 4, l15 = lane & 15;
  const int rg = blockIdx.x & 7, s = blockIdx.x >> 3;
  const int rbase = rg * 16;
  int* flag_me = flags + 16 + blockIdx.x;
  int* flag_pt = flags + 16 + (blockIdx.x ^ 8);
  ushort* buf_me = gbuf + (size_t)blockIdx.x * 2 * 4096;
  const ushort* buf_pt = gbuf + (size_t)(blockIdx.x ^ 8) * 2 * 4096;

  if (tid < VOC)
    biasl[tid] = (MODE == 0) ? bf2f(((const ushort*)fcbp)[tid]) : ((const float*)fcbp)[tid];

  // persistent W_hh fragments: wave owns global N-tiles nt0, nt0+1, full K.
  const int nt0 = s * 16 + 2 * wid;
  const uint4* Wf4 = (const uint4*)wf;
  bf16x8 Bo[2][8], Bp[2][8];
#pragma unroll
  for (int j = 0; j < 2; ++j)
#pragma unroll
    for (int ktl = 0; ktl < 8; ++ktl) {
      Bo[j][ktl] = *(const bf16x8*)(Wf4 + ((size_t)(nt0 + j) * 16 + (s * 8 + ktl)) * 64 + lane);
      Bp[j][ktl] = *(const bf16x8*)(Wf4 + ((size_t)(nt0 + j) * 16 + ((1 - s) * 8 + ktl)) * 64 + lane);
    }

  // stage own half of h_{-1} into LDS slot 0 + publish to gbuf parity 1
  {
    int g = tid >> 4, m = tid & 15;
    uint4 v;
    if (MODE == 0) {
      v = *(const uint4*)&((const ushort*)hiddenp)[(size_t)(rbase + m) * HID + s * 256 + g * 8];
    } else {
      const float* hf = (const float*)hiddenp;
      ushort tmp[8];
#pragma unroll
      for (int j = 0; j < 8; ++j) tmp[j] = f2bf(hf[(size_t)(rbase + m) * HID + s * 256 + g * 8 + j]);
      v = *(const uint4*)tmp;
    }
    *(uint4*)&hlds[0][g * LDS_G + m * 8] = v;
    uint64_t* dst = (uint64_t*)&buf_me[4096 + g * 128 + m * 8];
    const uint64_t* sv = (const uint64_t*)&v;
    __hip_atomic_store(dst, sv[0], __ATOMIC_RELAXED, __HIP_MEMORY_SCOPE_SYSTEM);
    __hip_atomic_store(dst + 1, sv[1], __ATOMIC_RELAXED, __HIP_MEMORY_SCOPE_SYSTEM);
  }
  __syncthreads();   // drains each wave's vmcnt before flag
  __atomic_signal_fence(__ATOMIC_SEQ_CST);
  if (tid == 0)
    __hip_atomic_store(flag_me, 1, __ATOMIC_RELAXED, __HIP_MEMORY_SCOPE_SYSTEM);

  const uint4* Ff4 = (const uint4*)fwf;
  float* outf = (float*)outp;
  ushort* outb = (ushort*)outp;
  const bool lw = (wid >= 5);
  const int lt = s * 3 + (wid - 5);

#pragma unroll 1
  for (int t = 0; t < SEQL; ++t) {
    const int need = t + 1;
    const int rslot = t & 1, wslot = (t + 1) & 1;
    int fv = __hip_atomic_load(flag_pt, __ATOMIC_RELAXED, __HIP_MEMORY_SCOPE_SYSTEM);
    // own-half A fragments (h_{t-1} cols [s*256, s*256+256))
    bf16x8 a[8];
#pragma unroll
    for (int ktl = 0; ktl < 8; ++ktl)
      a[ktl] = *(const bf16x8*)&hlds[rslot][(ktl * 4 + q) * LDS_G + l15 * 8];
    int xi[4];
#pragma unroll
    for (int rgi = 0; rgi < 4; ++rgi)
      xi[rgi] = x[(size_t)((rbase + q * 4 + rgi) * SEQL + t) * xstr];
    float ew[2][4];
#pragma unroll
    for (int j = 0; j < 2; ++j) {
      int n = (nt0 + j) * 16 + l15;
#pragma unroll
      for (int rgi = 0; rgi < 4; ++rgi) ew[j][rgi] = embwb[(size_t)xi[rgi] * HID + n];
    }
    f32x4 c0 = {0.f, 0.f, 0.f, 0.f}, c1 = {0.f, 0.f, 0.f, 0.f}, lc = {0.f, 0.f, 0.f, 0.f};
#pragma unroll
    for (int ktl = 0; ktl < 8; ++ktl) {
      c0 = __builtin_amdgcn_mfma_f32_16x16x32_bf16(a[ktl], Bo[0][ktl], c0, 0, 0, 0);
      c1 = __builtin_amdgcn_mfma_f32_16x16x32_bf16(a[ktl], Bo[1][ktl], c1, 0, 0, 0);
    }
    if (lw) {
#pragma unroll
      for (int ktl = 0; ktl < 8; ++ktl) {
        bf16x8 f = *(const bf16x8*)(Ff4 + ((size_t)lt * 16 + s * 8 + ktl) * 64 + lane);
        lc = __builtin_amdgcn_mfma_f32_16x16x32_bf16(a[ktl], f, lc, 0, 0, 0);
      }
    }
    // wait for partner's h_{t-1} half (fence-free: relaxed system poll)
    while (fv < need) {
      __builtin_amdgcn_s_sleep(1);
      fv = __hip_atomic_load(flag_pt, __ATOMIC_RELAXED, __HIP_MEMORY_SCOPE_SYSTEM);
    }
    __atomic_signal_fence(__ATOMIC_SEQ_CST);
    const ushort* pb = buf_pt + ((size_t)((t + 1) & 1)) * 4096;
    bf16x8 ap[8];
#pragma unroll
    for (int ktl = 0; ktl < 8; ++ktl) {
      const uint64_t* sp = (const uint64_t*)&pb[(ktl * 4 + q) * 128 + l15 * 8];
      uint64_t tmp[2];
      tmp[0] = __hip_atomic_load((uint64_t*)sp, __ATOMIC_RELAXED, __HIP_MEMORY_SCOPE_SYSTEM);
      tmp[1] = __hip_atomic_load((uint64_t*)sp + 1, __ATOMIC_RELAXED, __HIP_MEMORY_SCOPE_SYSTEM);
      ap[ktl] = *(const bf16x8*)tmp;
    }
#pragma unroll
    for (int ktl = 0; ktl < 8; ++ktl) {
      c0 = __builtin_amdgcn_mfma_f32_16x16x32_bf16(ap[ktl], Bp[0][ktl], c0, 0, 0, 0);
      c1 = __builtin_amdgcn_mfma_f32_16x16x32_bf16(ap[ktl], Bp[1][ktl], c1, 0, 0, 0);
    }
    if (lw) {
#pragma unroll
      for (int ktl = 0; ktl < 8; ++ktl) {
        bf16x8 f = *(const bf16x8*)(Ff4 + ((size_t)lt * 16 + (1 - s) * 8 + ktl) * 64 + lane);
        lc = __builtin_amdgcn_mfma_f32_16x16x32_bf16(ap[ktl], f, lc, 0, 0, 0);
      }
      if (t > 0) {
        int n = lt * 16 + l15;
        float bv = biasl[n];
#pragma unroll
        for (int rgi = 0; rgi < 4; ++rgi) {
          size_t idx = ((size_t)(rbase + q * 4 + rgi) * SEQL + (t - 1)) * VOC + n;
          float val = lc[rgi] + bv;
          if (MODE == 0) outb[idx] = f2bf(val); else outf[idx] = val;
        }
      }
    }
    // h_t = tanh(pre)
    ushort hv[2][4];
#pragma unroll
    for (int rgi = 0; rgi < 4; ++rgi) hv[0][rgi] = f2bf(fast_tanh(c0[rgi] + ew[0][rgi]));
#pragma unroll
    for (int rgi = 0; rgi < 4; ++rgi) hv[1][rgi] = f2bf(fast_tanh(c1[rgi] + ew[1][rgi]));
#pragma unroll
    for (int j = 0; j < 2; ++j) {
      int nl = (2 * wid + j) * 16 + l15;
      int base = (nl >> 3) * LDS_G + (nl & 7);
#pragma unroll
      for (int rgi = 0; rgi < 4; ++rgi) hlds[wslot][base + (q * 4 + rgi) * 8] = hv[j][rgi];
    }
    __syncthreads();   // h_t complete in LDS slot wslot
    {
      int g = tid >> 4, m = tid & 15;
      const uint64_t* sv = (const uint64_t*)&hlds[wslot][g * LDS_G + m * 8];
      uint64_t* dst = (uint64_t*)&buf_me[(size_t)(t & 1) * 4096 + g * 128 + m * 8];
      __hip_atomic_store(dst, sv[0], __ATOMIC_RELAXED, __HIP_MEMORY_SCOPE_SYSTEM);
      __hip_atomic_store(dst + 1, sv[1], __ATOMIC_RELAXED, __HIP_MEMORY_SCOPE_SYSTEM);
    }
    __syncthreads();   // drains every wave's vmcnt (publish stores at MALL)
    __atomic_signal_fence(__ATOMIC_SEQ_CST);
    if (tid == 0)
      __hip_atomic_store(flag_me, t + 2, __ATOMIC_RELAXED, __HIP_MEMORY_SCOPE_SYSTEM);
  }

  // epilogue: logits for t=1023 (h_1023 in LDS slot 0, partner parity 1)
  if (lw) {
    const int need = SEQL + 1;
    int fv = __hip_atomic_load(flag_pt, __ATOMIC_RELAXED, __HIP_MEMORY_SCOPE_SYSTEM);
    while (fv < need) {
      __builtin_amdgcn_s_sleep(1);
      fv = __hip_atomic_load(flag_pt, __ATOMIC_RELAXED, __HIP_MEMORY_SCOPE_SYSTEM);
    }
    __atomic_signal_fence(__ATOMIC_SEQ_CST);
    const ushort* pb = buf_pt + 4096;
    f32x4 lc = {0.f, 0.f, 0.f, 0.f};
#pragma unroll
    for (int ktl = 0; ktl < 8; ++ktl) {
      bf16x8 av = *(const bf16x8*)&hlds[0][(ktl * 4 + q) * LDS_G + l15 * 8];
      bf16x8 f = *(const bf16x8*)(Ff4 + ((size_t)lt * 16 + s * 8 + ktl) * 64 + lane);
      lc = __builtin_amdgcn_mfma_f32_16x16x32_bf16(av, f, lc, 0, 0, 0);
    }
#pragma unroll
    for (int ktl = 0; ktl < 8; ++ktl) {
      const uint64_t* sp = (const uint64_t*)&pb[(ktl * 4 + q) * 128 + l15 * 8];
      uint64_t tmp[2];
      tmp[0] = __hip_atomic_load((uint64_t*)sp, __ATOMIC_RELAXED, __HIP_MEMORY_SCOPE_SYSTEM);
      tmp[1] = __hip_atomic_load((uint64_t*)sp + 1, __ATOMIC_RELAXED, __HIP_MEMORY_SCOPE_SYSTEM);
      bf16x8 av = *(const bf16x8*)tmp;
      bf16x8 f = *(const bf16x8*)(Ff4 + ((size_t)lt * 16 + (1 - s) * 8 + ktl) * 64 + lane);
      lc = __builtin_amdgcn_mfma_f32_16x16x32_bf16(av, f, lc, 0, 0, 0);
    }
    int n = lt * 16 + l15;
    float bv = biasl[n];
#pragma unroll
    for (int rgi = 0; rgi < 4; ++rgi) {
      size_t idx = ((size_t)(rbase + q * 4 + rgi) * SEQL + (SEQL - 1)) * VOC + n;
      float val = lc[rgi] + bv;
      if (MODE == 0) outb[idx] = f2bf(val); else outf[idx] = val;
    }
  }
  {
    int g = tid >> 4, m = tid & 15;
    if (MODE == 0) {
      *(uint4*)&outb[(size_t)B_SZ * SEQL * VOC + (size_t)(rbase + m) * HID + s * 256 + g * 8] =
          *(const uint4*)&hlds[0][g * LDS_G + m * 8];
    } else {
      float* fh = outf + (size_t)B_SZ * SEQL * VOC;
#pragma unroll
      for (int j = 0; j < 8; ++j)
        fh[(size_t)(rbase + m) * HID + s * 256 + g * 8 + j] = bf2f(hlds[0][g * LDS_G + m * 8 + j]);
    }
  }
}

extern "C" void kernel_launch(void* const* d_in, const int* in_sizes, int n_in,
                              void* d_out, int out_size, void* d_ws, size_t ws_size,
                              hipStream_t stream) {
  const void* x      = d_in[0];
  const void* hidden = d_in[1];
  const void* emb    = d_in[2];
  const void* wxh    = d_in[3];
  const void* whh    = d_in[4];
  const void* bh     = d_in[5];
  const void* fcw    = d_in[6];
  const void* fcb    = d_in[7];

  char* ws = (char*)d_ws;
  int*    flags  = (int*)ws;                                      // 256 B
  float*  embwb  = (float*)(ws + 256);                            // 196608 B
  ushort* wfrag  = (ushort*)(ws + 256 + 196608);                  // 524288 B
  ushort* fwfrag = (ushort*)(ws + 256 + 196608 + 524288);         // 98304 B
  ushort* gbuf   = (ushort*)(ws + 256 + 196608 + 524288 + 98304); // 262144 B

  detect_kernel<<<1, 64, 0, stream>>>((const ushort*)emb, (const int*)x, flags);

  prep_embw<0><<<192, 256, 0, stream>>>(emb, wxh, bh, flags, embwb);
  prep_embw<1><<<192, 256, 0, stream>>>(emb, wxh, bh, flags, embwb);
  prep_frag<0><<<128, 256, 0, stream>>>(whh, flags, wfrag, HID);
  prep_frag<1><<<128, 256, 0, stream>>>(whh, flags, wfrag, HID);
  prep_frag<0><<<24, 256, 0, stream>>>(fcw, flags, fwfrag, VOC);
  prep_frag<1><<<24, 256, 0, stream>>>(fcw, flags, fwfrag, VOC);

  rnn_split<0><<<16, 512, 0, stream>>>((const int*)x, hidden, embwb, wfrag, fwfrag, fcb, flags, gbuf, d_out);
  rnn_split<1><<<16, 512, 0, stream>>>((const int*)x, hidden, embwb, wfrag, fwfrag, fcb, flags, gbuf, d_out);
}

// Round 5
// 3504.206 us; speedup vs baseline: 3.4150x; 1.0615x over previous
//
#include <hip/hip_runtime.h>
#include <stdint.h>

#define B_SZ 128
#define SEQL 1024
#define EMB  64
#define HID  512
#define VOC  96
#define LDS_G 136
#define PKT  1536   // 512 threads * 3 packets per parity

typedef __attribute__((ext_vector_type(8))) short bf16x8;
typedef __attribute__((ext_vector_type(4))) float f32x4;

__device__ __forceinline__ float bf2f(ushort u) {
  union { uint32_t i; float f; } c; c.i = ((uint32_t)u) << 16; return c.f;
}
__device__ __forceinline__ ushort f2bf(float f) {
  union { float f; uint32_t i; } c; c.f = f;
  uint32_t u = c.i;
  return (ushort)((u + 0x7fffu + ((u >> 16) & 1u)) >> 16);
}
__device__ __forceinline__ float fast_tanh(float v) {
  float e = __expf(2.0f * v);
  return (e - 1.0f) * __builtin_amdgcn_rcpf(e + 1.0f);
}
__device__ __forceinline__ uint64_t pack3(ushort a, ushort b, ushort c, uint32_t tag) {
  return (uint64_t)a | ((uint64_t)b << 16) | ((uint64_t)c << 32) | ((uint64_t)tag << 48);
}
__device__ __forceinline__ uint64_t pload(const uint64_t* p) {
  return __hip_atomic_load((uint64_t*)p, __ATOMIC_RELAXED, __HIP_MEMORY_SCOPE_SYSTEM);
}
__device__ __forceinline__ void pstore(uint64_t* p, uint64_t v) {
  __hip_atomic_store(p, v, __ATOMIC_RELAXED, __HIP_MEMORY_SCOPE_SYSTEM);
}

// flags[0]=dtype mode (0 bf16 / 1 f32); flags[1]=x stride (1 int32 / 2 int64)
__global__ void detect_kernel(const ushort* __restrict__ emb_u16,
                              const int* __restrict__ x32, int* __restrict__ flags) {
  if (blockIdx.x != 0 || threadIdx.x != 0) return;
  int wild = 0;
  for (int i = 0; i < 256; ++i) {
    ushort u = emb_u16[i];
    int ex = (u >> 7) & 0xFF;
    if (u != 0 && (ex < 96 || ex > 159)) wild++;
  }
  flags[0] = (wild > 8) ? 1 : 0;
  int allz = 1, anynz = 0;
  for (int i = 0; i < 64; ++i) {
    if (x32[2 * i + 1] != 0) allz = 0;
    if (x32[2 * i] != 0) anynz = 1;
  }
  flags[1] = (allz && anynz) ? 2 : 1;
}

template <int MODE>
__global__ void prep_embw(const void* __restrict__ embp, const void* __restrict__ wxhp,
                          const void* __restrict__ bhp, const int* __restrict__ flags,
                          float* __restrict__ embwb) {
  if (flags[0] != MODE) return;
  int gt = blockIdx.x * 256 + threadIdx.x;
  int v = gt >> 9, h = gt & 511;
  float s;
  if (MODE == 0) {
    const ushort* emb = (const ushort*)embp;
    const ushort* wxh = (const ushort*)wxhp;
    s = bf2f(((const ushort*)bhp)[h]);
#pragma unroll 8
    for (int e = 0; e < EMB; ++e) s += bf2f(emb[v * EMB + e]) * bf2f(wxh[e * HID + h]);
  } else {
    const float* emb = (const float*)embp;
    const float* wxh = (const float*)wxhp;
    s = ((const float*)bhp)[h];
#pragma unroll 8
    for (int e = 0; e < EMB; ++e) s += emb[v * EMB + e] * wxh[e * HID + h];
  }
  embwb[gt] = s;
}

template <int MODE>
__global__ void prep_frag(const void* __restrict__ Wp, const int* __restrict__ flags,
                          ushort* __restrict__ out, int ncols) {
  if (flags[0] != MODE) return;
  int t = blockIdx.x * 256 + threadIdx.x;
  int lane = t & 63, kt = (t >> 6) & 15, nt = t >> 10;
  int n = nt * 16 + (lane & 15);
  int k0 = kt * 32 + (lane >> 4) * 8;
  ushort* o = out + (size_t)t * 8;
  if (MODE == 0) {
    const ushort* W = (const ushort*)Wp;
#pragma unroll
    for (int j = 0; j < 8; ++j) o[j] = W[(size_t)(k0 + j) * ncols + n];
  } else {
    const float* W = (const float*)Wp;
#pragma unroll
    for (int j = 0; j < 8; ++j) o[j] = f2bf(W[(size_t)(k0 + j) * ncols + n]);
  }
}

// ---- recurrence, 2-way N-split, register-persistent W_hh halves,
//      flag-free tagged-packet h-exchange + cooperative LDS staging ----
template <int MODE>
__global__ __launch_bounds__(512, 2) void rnn_split(
    const int* __restrict__ x, const void* __restrict__ hiddenp,
    const float* __restrict__ embwb, const ushort* __restrict__ wf,
    const ushort* __restrict__ fwf, const void* __restrict__ fcbp,
    const int* __restrict__ flags, uint64_t* __restrict__ gbuf, void* __restrict__ outp) {
  if (flags[0] != MODE) return;
  const int xstr = flags[1];
  __shared__ __align__(16) ushort hlds[2][32 * LDS_G + 8];  // own half, dbuf
  __shared__ __align__(16) ushort plds[2][32 * LDS_G + 8];  // partner half, dbuf
  __shared__ float biasl[VOC];
  const int tid = threadIdx.x;
  const int wid = tid >> 6, lane = tid & 63;
  const int q = lane >> 4, l15 = lane & 15;
  const int rg = blockIdx.x & 7, s = blockIdx.x >> 3;
  const int rbase = rg * 16;
  uint64_t* pkt_me = gbuf + (size_t)blockIdx.x * 2 * PKT;
  const uint64_t* pkt_pt = gbuf + (size_t)(blockIdx.x ^ 8) * 2 * PKT;

  if (tid < VOC)
    biasl[tid] = (MODE == 0) ? bf2f(((const ushort*)fcbp)[tid]) : ((const float*)fcbp)[tid];

  // persistent W_hh fragments: wave owns global N-tiles nt0, nt0+1, full K.
  const int nt0 = s * 16 + 2 * wid;
  const uint4* Wf4 = (const uint4*)wf;
  bf16x8 Bo[2][8], Bp[2][8];
#pragma unroll
  for (int j = 0; j < 2; ++j)
#pragma unroll
    for (int ktl = 0; ktl < 8; ++ktl) {
      Bo[j][ktl] = *(const bf16x8*)(Wf4 + ((size_t)(nt0 + j) * 16 + (s * 8 + ktl)) * 64 + lane);
      Bp[j][ktl] = *(const bf16x8*)(Wf4 + ((size_t)(nt0 + j) * 16 + ((1 - s) * 8 + ktl)) * 64 + lane);
    }

  // stage own half of h_{-1} into hlds[0] (contiguous)
  {
    int g = tid >> 4, m = tid & 15;
    uint4 v;
    if (MODE == 0) {
      v = *(const uint4*)&((const ushort*)hiddenp)[(size_t)(rbase + m) * HID + s * 256 + g * 8];
    } else {
      const float* hf = (const float*)hiddenp;
      ushort tmp[8];
#pragma unroll
      for (int j = 0; j < 8; ++j) tmp[j] = f2bf(hf[(size_t)(rbase + m) * HID + s * 256 + g * 8 + j]);
      v = *(const uint4*)tmp;
    }
    *(uint4*)&hlds[0][g * LDS_G + m * 8] = v;
  }
  // initial packet publish: h_{-1}, tag 1, parity 1 (producer step t=-1)
  {
    ushort v8[8];
#pragma unroll
    for (int k = 0; k < 8; ++k) {
      int j = k >> 2, i = k & 3;
      size_t r = rbase + q * 4 + i;
      size_t c = s * 256 + (2 * wid + j) * 16 + l15;
      v8[k] = (MODE == 0) ? ((const ushort*)hiddenp)[r * HID + c]
                          : f2bf(((const float*)hiddenp)[r * HID + c]);
    }
    uint64_t* dst = pkt_me + PKT + (size_t)tid * 3;
    pstore(dst + 0, pack3(v8[0], v8[1], v8[2], 1));
    pstore(dst + 1, pack3(v8[3], v8[4], v8[5], 1));
    pstore(dst + 2, pack3(v8[6], v8[7], 0, 1));
  }
  __syncthreads();

  const uint4* Ff4 = (const uint4*)fwf;
  float* outf = (float*)outp;
  ushort* outb = (ushort*)outp;
  const bool lw = (wid >= 5);
  const int lt = s * 3 + (wid - 5);

#pragma unroll 1
  for (int t = 0; t < SEQL; ++t) {
    const int rslot = t & 1, wslot = (t + 1) & 1, pp = (t + 1) & 1;
    const uint32_t tag = (uint32_t)(t + 1);
    const uint64_t* psrc = pkt_pt + (size_t)pp * PKT + (size_t)tid * 3;
    // issue partner packet loads early (overlap MALL RT with own compute)
    uint64_t p0 = pload(psrc + 0);
    uint64_t p1 = pload(psrc + 1);
    uint64_t p2 = pload(psrc + 2);

    // own-half A fragments
    bf16x8 a[8];
#pragma unroll
    for (int ktl = 0; ktl < 8; ++ktl)
      a[ktl] = *(const bf16x8*)&hlds[rslot][(ktl * 4 + q) * LDS_G + l15 * 8];
    int xi[4];
#pragma unroll
    for (int rgi = 0; rgi < 4; ++rgi)
      xi[rgi] = x[(size_t)((rbase + q * 4 + rgi) * SEQL + t) * xstr];
    float ew[2][4];
#pragma unroll
    for (int j = 0; j < 2; ++j) {
      int n = (nt0 + j) * 16 + l15;
#pragma unroll
      for (int rgi = 0; rgi < 4; ++rgi) ew[j][rgi] = embwb[(size_t)xi[rgi] * HID + n];
    }
    f32x4 c0 = {0.f, 0.f, 0.f, 0.f}, c1 = {0.f, 0.f, 0.f, 0.f}, lc = {0.f, 0.f, 0.f, 0.f};
#pragma unroll
    for (int ktl = 0; ktl < 8; ++ktl) {
      c0 = __builtin_amdgcn_mfma_f32_16x16x32_bf16(a[ktl], Bo[0][ktl], c0, 0, 0, 0);
      c1 = __builtin_amdgcn_mfma_f32_16x16x32_bf16(a[ktl], Bo[1][ktl], c1, 0, 0, 0);
    }
    if (lw) {
#pragma unroll
      for (int ktl = 0; ktl < 8; ++ktl) {
        bf16x8 f = *(const bf16x8*)(Ff4 + ((size_t)lt * 16 + s * 8 + ktl) * 64 + lane);
        lc = __builtin_amdgcn_mfma_f32_16x16x32_bf16(a[ktl], f, lc, 0, 0, 0);
      }
    }

    // validate tags (data is the flag), retry only misses
    while ((uint32_t)(p0 >> 48) != tag) { __builtin_amdgcn_s_sleep(1); p0 = pload(psrc + 0); }
    while ((uint32_t)(p1 >> 48) != tag) { __builtin_amdgcn_s_sleep(1); p1 = pload(psrc + 1); }
    while ((uint32_t)(p2 >> 48) != tag) { __builtin_amdgcn_s_sleep(1); p2 = pload(psrc + 2); }
    // unpack to partner LDS staging in A-frag layout
    {
      ushort w8[8] = {(ushort)p0, (ushort)(p0 >> 16), (ushort)(p0 >> 32),
                      (ushort)p1, (ushort)(p1 >> 16), (ushort)(p1 >> 32),
                      (ushort)p2, (ushort)(p2 >> 16)};
#pragma unroll
      for (int k = 0; k < 8; ++k) {
        int j = k >> 2, i = k & 3;
        int c = (2 * wid + j) * 16 + l15;
        int r = q * 4 + i;
        plds[pp][(c >> 3) * LDS_G + r * 8 + (c & 7)] = w8[k];
      }
    }
    __syncthreads();   // plds[pp] complete

    bf16x8 ap[8];
#pragma unroll
    for (int ktl = 0; ktl < 8; ++ktl)
      ap[ktl] = *(const bf16x8*)&plds[pp][(ktl * 4 + q) * LDS_G + l15 * 8];
#pragma unroll
    for (int ktl = 0; ktl < 8; ++ktl) {
      c0 = __builtin_amdgcn_mfma_f32_16x16x32_bf16(ap[ktl], Bp[0][ktl], c0, 0, 0, 0);
      c1 = __builtin_amdgcn_mfma_f32_16x16x32_bf16(ap[ktl], Bp[1][ktl], c1, 0, 0, 0);
    }
    if (lw) {
#pragma unroll
      for (int ktl = 0; ktl < 8; ++ktl) {
        bf16x8 f = *(const bf16x8*)(Ff4 + ((size_t)lt * 16 + (1 - s) * 8 + ktl) * 64 + lane);
        lc = __builtin_amdgcn_mfma_f32_16x16x32_bf16(ap[ktl], f, lc, 0, 0, 0);
      }
      if (t > 0) {
        int n = lt * 16 + l15;
        float bv = biasl[n];
#pragma unroll
        for (int rgi = 0; rgi < 4; ++rgi) {
          size_t idx = ((size_t)(rbase + q * 4 + rgi) * SEQL + (t - 1)) * VOC + n;
          float val = lc[rgi] + bv;
          if (MODE == 0) outb[idx] = f2bf(val); else outf[idx] = val;
        }
      }
    }

    // h_t = tanh(pre); publish straight from registers (tag t+2, parity t&1)
    ushort hv[8];
#pragma unroll
    for (int rgi = 0; rgi < 4; ++rgi) hv[rgi]     = f2bf(fast_tanh(c0[rgi] + ew[0][rgi]));
#pragma unroll
    for (int rgi = 0; rgi < 4; ++rgi) hv[4 + rgi] = f2bf(fast_tanh(c1[rgi] + ew[1][rgi]));
    {
      uint64_t* dst = pkt_me + (size_t)(t & 1) * PKT + (size_t)tid * 3;
      uint32_t ntag = (uint32_t)(t + 2);
      pstore(dst + 0, pack3(hv[0], hv[1], hv[2], ntag));
      pstore(dst + 1, pack3(hv[3], hv[4], hv[5], ntag));
      pstore(dst + 2, pack3(hv[6], hv[7], 0, ntag));
    }
#pragma unroll
    for (int j = 0; j < 2; ++j) {
      int nl = (2 * wid + j) * 16 + l15;
      int base = (nl >> 3) * LDS_G + (nl & 7);
#pragma unroll
      for (int rgi = 0; rgi < 4; ++rgi) hlds[wslot][base + (q * 4 + rgi) * 8] = hv[j * 4 + rgi];
    }
    __syncthreads();   // hlds[wslot] ready for next iteration
  }

  // epilogue: logits for t=1023 (own h in hlds[0]; partner via tag 1025, parity 1)
  {
    const uint32_t tag = (uint32_t)(SEQL + 1);
    const uint64_t* psrc = pkt_pt + PKT + (size_t)tid * 3;
    uint64_t p0 = pload(psrc + 0);
    uint64_t p1 = pload(psrc + 1);
    uint64_t p2 = pload(psrc + 2);
    while ((uint32_t)(p0 >> 48) != tag) { __builtin_amdgcn_s_sleep(1); p0 = pload(psrc + 0); }
    while ((uint32_t)(p1 >> 48) != tag) { __builtin_amdgcn_s_sleep(1); p1 = pload(psrc + 1); }
    while ((uint32_t)(p2 >> 48) != tag) { __builtin_amdgcn_s_sleep(1); p2 = pload(psrc + 2); }
    ushort w8[8] = {(ushort)p0, (ushort)(p0 >> 16), (ushort)(p0 >> 32),
                    (ushort)p1, (ushort)(p1 >> 16), (ushort)(p1 >> 32),
                    (ushort)p2, (ushort)(p2 >> 16)};
#pragma unroll
    for (int k = 0; k < 8; ++k) {
      int j = k >> 2, i = k & 3;
      int c = (2 * wid + j) * 16 + l15;
      int r = q * 4 + i;
      plds[1][(c >> 3) * LDS_G + r * 8 + (c & 7)] = w8[k];
    }
  }
  __syncthreads();
  if (lw) {
    f32x4 lc = {0.f, 0.f, 0.f, 0.f};
#pragma unroll
    for (int ktl = 0; ktl < 8; ++ktl) {
      bf16x8 av = *(const bf16x8*)&hlds[0][(ktl * 4 + q) * LDS_G + l15 * 8];
      bf16x8 f = *(const bf16x8*)(Ff4 + ((size_t)lt * 16 + s * 8 + ktl) * 64 + lane);
      lc = __builtin_amdgcn_mfma_f32_16x16x32_bf16(av, f, lc, 0, 0, 0);
    }
#pragma unroll
    for (int ktl = 0; ktl < 8; ++ktl) {
      bf16x8 av = *(const bf16x8*)&plds[1][(ktl * 4 + q) * LDS_G + l15 * 8];
      bf16x8 f = *(const bf16x8*)(Ff4 + ((size_t)lt * 16 + (1 - s) * 8 + ktl) * 64 + lane);
      lc = __builtin_amdgcn_mfma_f32_16x16x32_bf16(av, f, lc, 0, 0, 0);
    }
    int n = lt * 16 + l15;
    float bv = biasl[n];
#pragma unroll
    for (int rgi = 0; rgi < 4; ++rgi) {
      size_t idx = ((size_t)(rbase + q * 4 + rgi) * SEQL + (SEQL - 1)) * VOC + n;
      float val = lc[rgi] + bv;
      if (MODE == 0) outb[idx] = f2bf(val); else outf[idx] = val;
    }
  }
  {
    int g = tid >> 4, m = tid & 15;
    if (MODE == 0) {
      *(uint4*)&outb[(size_t)B_SZ * SEQL * VOC + (size_t)(rbase + m) * HID + s * 256 + g * 8] =
          *(const uint4*)&hlds[0][g * LDS_G + m * 8];
    } else {
      float* fh = outf + (size_t)B_SZ * SEQL * VOC;
#pragma unroll
      for (int j = 0; j < 8; ++j)
        fh[(size_t)(rbase + m) * HID + s * 256 + g * 8 + j] = bf2f(hlds[0][g * LDS_G + m * 8 + j]);
    }
  }
}

extern "C" void kernel_launch(void* const* d_in, const int* in_sizes, int n_in,
                              void* d_out, int out_size, void* d_ws, size_t ws_size,
                              hipStream_t stream) {
  const void* x      = d_in[0];
  const void* hidden = d_in[1];
  const void* emb    = d_in[2];
  const void* wxh    = d_in[3];
  const void* whh    = d_in[4];
  const void* bh     = d_in[5];
  const void* fcw    = d_in[6];
  const void* fcb    = d_in[7];

  char* ws = (char*)d_ws;
  int*      flags  = (int*)ws;                                      // 256 B
  float*    embwb  = (float*)(ws + 256);                            // 196608 B
  ushort*   wfrag  = (ushort*)(ws + 256 + 196608);                  // 524288 B
  ushort*   fwfrag = (ushort*)(ws + 256 + 196608 + 524288);         // 98304 B
  uint64_t* gbuf   = (uint64_t*)(ws + 256 + 196608 + 524288 + 98304); // 393216 B

  detect_kernel<<<1, 64, 0, stream>>>((const ushort*)emb, (const int*)x, flags);

  prep_embw<0><<<192, 256, 0, stream>>>(emb, wxh, bh, flags, embwb);
  prep_embw<1><<<192, 256, 0, stream>>>(emb, wxh, bh, flags, embwb);
  prep_frag<0><<<128, 256, 0, stream>>>(whh, flags, wfrag, HID);
  prep_frag<1><<<128, 256, 0, stream>>>(whh, flags, wfrag, HID);
  prep_frag<0><<<24, 256, 0, stream>>>(fcw, flags, fwfrag, VOC);
  prep_frag<1><<<24, 256, 0, stream>>>(fcw, flags, fwfrag, VOC);

  rnn_split<0><<<16, 512, 0, stream>>>((const int*)x, hidden, embwb, wfrag, fwfrag, fcb, flags, gbuf, d_out);
  rnn_split<1><<<16, 512, 0, stream>>>((const int*)x, hidden, embwb, wfrag, fwfrag, fcb, flags, gbuf, d_out);
}